// Round 2
// baseline (108.106 us; speedup 1.0000x reference)
//
#include <hip/hip_runtime.h>

#define NB   256        // bins per batch (power of two, == TPB)
#define TPB  256
#define NI   (NB + 1)   // 257 intervals around/between sorted bins
#define G    128        // chunks per batch -> 512 blocks = 2/CU
#define MINF 1e30f
#define CAPD 1e15f      // cap so d*d == 1e30 == reference BIG when a side is empty

// ---- single fused kernel (init done by host-side memsets, finalize by last block) ----
__global__ __launch_bounds__(TPB, 2) void k_all(
    const float* __restrict__ bc, const float* __restrict__ gt,
    int V, int CH, int B,
    float* __restrict__ sumA_part, int* __restrict__ cnt_part,
    unsigned* __restrict__ gmin, unsigned* __restrict__ gmax,
    float* __restrict__ sbins, unsigned* __restrict__ counter,
    float* __restrict__ out)
{
    const int tid  = threadIdx.x;
    const int b    = blockIdx.x / G;
    const int blk  = blockIdx.x % G;
    const int lane = tid & 63, w = tid >> 6;

    __shared__ float    c[NB];
    __shared__ unsigned imn[NI], imx[NI];
    __shared__ float r4[4]; __shared__ int i4[4];

    // ---- phase 1: sort this batch's bins in LDS (every block, in parallel) ----
    c[tid] = bc[b * NB + tid];
    for (int t = tid; t < NI; t += TPB) { imn[t] = 0xFFFFFFFFu; imx[t] = 0u; }
    __syncthreads();
    for (int k = 2; k <= NB; k <<= 1)
        for (int j = k >> 1; j > 0; j >>= 1) {
            const int ixj = tid ^ j;
            if (ixj > tid) {
                const float a = c[tid], bv = c[ixj];
                if ((a > bv) == ((tid & k) == 0)) { c[tid] = bv; c[ixj] = a; }
            }
            __syncthreads();
        }
    if (blk == 0) sbins[b * NB + tid] = c[tid];   // finalize needs all batches' sorted bins

    // ---- phase 2: point loop (identical math/order to verified 3-kernel version) ----
    const int start = blk * CH;
    const int cn = min(CH, V - start);
    const float* __restrict__ gp = gt + (size_t)b * V + start;

    float sum = 0.f; int cnt = 0;
    for (int i = tid; i < cn; i += TPB) {
        const float q = gp[i];
        if (q >= 0.001f) {
            // branchless lower-bound: idx = #bins <= q, in [0,256]
            int idx = 0;
            #pragma unroll
            for (int st = 128; st >= 1; st >>= 1)
                idx += (c[idx + st - 1] <= q) ? st : 0;
            idx += (c[idx] <= q) ? 1 : 0;   // only fires when idx==255 & c[255]<=q
            const float dlo = (idx > 0)  ? (q - c[idx - 1]) : MINF;
            const float dhi = (idx < NB) ? (c[idx] - q)     : MINF;
            const float d = fminf(dlo, dhi);
            sum += d * d; ++cnt;
            // nonneg float bits order as uints -> exact LDS min/max
            atomicMin(&imn[idx], __float_as_uint(q));
            atomicMax(&imx[idx], __float_as_uint(q));
        }
    }
    __syncthreads();

    // ---- phase 3: one device atomic per NON-EMPTY interval (init'd by memset) ----
    for (int t = tid; t < NI; t += TPB) {
        const unsigned lo = imn[t], hi = imx[t];
        if (lo != 0xFFFFFFFFu) atomicMin(&gmin[b * NI + t], lo);
        if (hi != 0u)          atomicMax(&gmax[b * NI + t], hi);
    }

    // deterministic block reduce of dir-1 sum + valid count
    for (int off = 32; off; off >>= 1) {
        sum += __shfl_down(sum, off);
        cnt += __shfl_down(cnt, off);
    }
    if (lane == 0) { r4[w] = sum; i4[w] = cnt; }
    __syncthreads();
    if (tid == 0) {
        sumA_part[blockIdx.x] = r4[0] + r4[1] + r4[2] + r4[3];
        cnt_part [blockIdx.x] = i4[0] + i4[1] + i4[2] + i4[3];
    }

    // ---- last-block-done handoff (release: wbL2 before counter bump) ----
    __threadfence();
    __syncthreads();
    __shared__ int lastFlag;
    if (tid == 0) lastFlag = (atomicAdd(counter, 1u) == (unsigned)(gridDim.x - 1));
    __syncthreads();
    if (!lastFlag) return;
    __threadfence();          // acquire: invalidate stale cache lines before reads

    // ---- phase 4: finalize (last block only) ----
    __shared__ float ssa[8]; __shared__ int sn[8];
    __shared__ float wtop[4], wbot[4], q4[4];

    // per-batch dir-1 sum + valid count (Lmax needs all batches first)
    for (int bb = 0; bb < B; ++bb) {
        float s = 0.f; int cc = 0;
        for (int k = tid; k < G; k += TPB) {      // G==TPB/2: one coalesced round
            s  += sumA_part[bb * G + k];
            cc += cnt_part [bb * G + k];
        }
        for (int off = 32; off; off >>= 1) { s += __shfl_down(s, off); cc += __shfl_down(cc, off); }
        if (lane == 0) { r4[w] = s; i4[w] = cc; }
        __syncthreads();
        if (tid == 0) { ssa[bb] = r4[0]+r4[1]+r4[2]+r4[3]; sn[bb] = i4[0]+i4[1]+i4[2]+i4[3]; }
        __syncthreads();
    }
    int Lmax = 0;
    for (int bb = 0; bb < B; ++bb) Lmax = max(Lmax, sn[bb]);

    float total = 0.f;
    for (int bb = 0; bb < B; ++bb) {
        // interval max (for pred, entries 0..255) / min (for succ, entries 1..256)
        const unsigned hib = gmax[bb * NI + tid];
        const unsigned lob = gmin[bb * NI + tid + 1];
        float pv = (hib == 0u)          ? -MINF : __uint_as_float(hib);
        float sv = (lob == 0xFFFFFFFFu) ?  MINF : __uint_as_float(lob);

        // wave-level inclusive prefix-max (pv) / inclusive suffix-min (sv)
        #pragma unroll
        for (int off = 1; off < 64; off <<= 1) {
            const float o = __shfl_up(pv, off);
            if (lane >= off) pv = fmaxf(pv, o);
        }
        #pragma unroll
        for (int off = 1; off < 64; off <<= 1) {
            const float o = __shfl_down(sv, off);
            if (lane < 64 - off) sv = fminf(sv, o);
        }
        if (lane == 63) wtop[w] = pv;   // full-wave max
        if (lane == 0)  wbot[w] = sv;   // full-wave min
        __syncthreads();
        #pragma unroll
        for (int ww = 0; ww < 4; ++ww) {
            if (ww < w) pv = fmaxf(pv, wtop[ww]);
            if (ww > w) sv = fminf(sv, wbot[ww]);
        }

        // bin tid: pred = max point < c, succ = min point >= c
        const float cj = sbins[bb * NB + tid];
        const float c2 = cj * cj;
        const float d  = fminf(fminf(cj - pv, sv - cj), CAPD);
        float bm = d * d;                       // == 1e30 (BIG) if no valid points
        const int npad = Lmax - sn[bb];
        if (npad > 0) bm = fminf(bm, c2);       // pad points sit at 0 -> dist c^2
        float s = bm, mc = c2;
        for (int off = 32; off; off >>= 1) {
            s  += __shfl_down(s, off);
            mc  = fminf(mc, __shfl_down(mc, off));
        }
        if (lane == 0) { r4[w] = s; q4[w] = mc; }
        __syncthreads();
        if (tid == 0)
            total += ssa[bb]
                   + (float)npad * fminf(fminf(q4[0], q4[1]), fminf(q4[2], q4[3]))
                   + (r4[0] + r4[1] + r4[2] + r4[3]);
        __syncthreads();                        // protect r4/q4/wtop/wbot reuse next batch
    }
    if (tid == 0) out[0] = total / (float)B;    // batch_reduction = mean
}

extern "C" void kernel_launch(void* const* d_in, const int* in_sizes, int n_in,
                              void* d_out, int out_size, void* d_ws, size_t ws_size,
                              hipStream_t stream) {
    const float* bc = (const float*)d_in[0];    // [B, 256, 1]
    const float* gt = (const float*)d_in[1];    // [B, 1, H, W]
    const int B  = in_sizes[0] / NB;            // 4
    const int V  = in_sizes[1] / B;             // 157696
    const int CH = (V + G - 1) / G;             // 1232

    float*    sbins     = (float*)d_ws;                         // [B, NB]
    float*    sumA_part = sbins + (size_t)B * NB;               // [B*G]
    int*      cnt_part  = (int*)(sumA_part + (size_t)B * G);    // [B*G]
    unsigned* gmin      = (unsigned*)(cnt_part + (size_t)B * G);// [B, NI]
    unsigned* gmax      = gmin + (size_t)B * NI;                // [B, NI]
    unsigned* counter   = gmax + (size_t)B * NI;                // [1]

    // init atomic targets + counter (stream-ordered before k_all; graph-capturable)
    hipMemsetAsync(gmin, 0xFF, (size_t)B * NI * sizeof(unsigned), stream);          // uint MIN identity
    hipMemsetAsync(gmax, 0x00, (size_t)B * NI * sizeof(unsigned) + sizeof(unsigned), // MAX identity + counter=0
                   stream);

    k_all<<<B * G, TPB, 0, stream>>>(bc, gt, V, CH, B,
                                     sumA_part, cnt_part, gmin, gmax,
                                     sbins, counter, (float*)d_out);
}

// Round 3
// 77.500 us; speedup vs baseline: 1.3949x; 1.3949x over previous
//
#include <hip/hip_runtime.h>

#define NB   256        // bins per batch (power of two, == TPB)
#define TPB  256
#define NI   (NB + 1)   // 257 intervals around/between sorted bins
#define G    128        // chunks per batch -> 512 blocks = 2/CU
#define P    5          // points per thread, processed with 5-way ILP (CH=1232 = 4.8125*TPB)
#define MINF 1e30f
#define CAPD 1e15f      // cap so d*d == 1e30 == reference BIG when a side is empty

// ---- kernel 1: bitonic-sort each batch's bins + init global interval arrays ----
__global__ __launch_bounds__(NB) void k_sort(const float* __restrict__ bc,
                                             float* __restrict__ sbins,
                                             unsigned* __restrict__ gmin,
                                             unsigned* __restrict__ gmax) {
    __shared__ float s[NB];
    const int tid = threadIdx.x, b = blockIdx.x;
    s[tid] = bc[b * NB + tid];
    // init atomic-reduce targets (runs before k_main; stream order guarantees visibility)
    for (int t = tid; t < NI; t += NB) {
        gmin[b * NI + t] = 0xFFFFFFFFu;   // identity for uint atomicMin on nonneg floats
        gmax[b * NI + t] = 0u;            // identity for uint atomicMax on nonneg floats
    }
    __syncthreads();
    for (int k = 2; k <= NB; k <<= 1)
        for (int j = k >> 1; j > 0; j >>= 1) {
            const int ixj = tid ^ j;
            if (ixj > tid) {
                const float a = s[tid], bv = s[ixj];
                if ((a > bv) == ((tid & k) == 0)) { s[tid] = bv; s[ixj] = a; }
            }
            __syncthreads();
        }
    sbins[b * NB + tid] = s[tid];
}

// ---- kernel 2: per point: binary-search sorted bins -> dir-1 sum + count;
//      per-interval point min/max via LDS, then ONE device atomic per interval.
//      The P searches per thread run in LOCKSTEP: each of the 9 stages issues P
//      independent ds_reads, amortizing the ~120cy LDS latency P-way.
//      Accumulation order (sum += d*d in ascending i) is bitwise-identical to
//      the verified sequential version. ----
__global__ __launch_bounds__(TPB) void k_main(
    const float* __restrict__ sbins, const float* __restrict__ gt,
    int V, int CH,
    float* __restrict__ sumA_part, int* __restrict__ cnt_part,
    unsigned* __restrict__ gmin, unsigned* __restrict__ gmax)
{
    const int b   = blockIdx.x / G;
    const int blk = blockIdx.x % G;
    const int tid = threadIdx.x;
    const int start = blk * CH;
    const int cn = min(CH, V - start);
    const float* __restrict__ gp = gt + (size_t)b * V + start;

    __shared__ float    c[NB];
    __shared__ unsigned imn[NI], imx[NI];
    c[tid] = sbins[b * NB + tid];
    for (int t = tid; t < NI; t += TPB) { imn[t] = 0xFFFFFFFFu; imx[t] = 0u; }
    __syncthreads();

    // gather phase: P independent global loads (one vmcnt drain, not P serial ones)
    float q[P];
    #pragma unroll
    for (int p = 0; p < P; ++p) {
        const int i = tid + p * TPB;
        q[p] = (i < cn) ? gp[i] : -1.f;          // sentinel: bins are >=0, so searches no-op
    }

    // lockstep branchless lower-bound: idx[p] = #bins <= q[p], in [0,256]
    int idx[P];
    #pragma unroll
    for (int p = 0; p < P; ++p) idx[p] = 0;
    #pragma unroll
    for (int st = 128; st >= 1; st >>= 1) {
        #pragma unroll
        for (int p = 0; p < P; ++p)
            idx[p] += (c[idx[p] + st - 1] <= q[p]) ? st : 0;
    }
    #pragma unroll
    for (int p = 0; p < P; ++p)
        idx[p] += (c[idx[p]] <= q[p]) ? 1 : 0;   // only fires when idx==255 & c[255]<=q

    // accumulate in ascending-p (== ascending-i) order: bitwise-same sum as before
    float sum = 0.f; int cnt = 0;
    #pragma unroll
    for (int p = 0; p < P; ++p) {
        if (q[p] >= 0.001f) {
            const float dlo = (idx[p] > 0)  ? (q[p] - c[idx[p] - 1]) : MINF;
            const float dhi = (idx[p] < NB) ? (c[idx[p]] - q[p])     : MINF;
            const float d = fminf(dlo, dhi);
            sum += d * d; ++cnt;
            // nonneg float bits order as uints -> exact LDS min/max
            atomicMin(&imn[idx[p]], __float_as_uint(q[p]));
            atomicMax(&imx[idx[p]], __float_as_uint(q[p]));
        }
    }
    __syncthreads();

    // one device atomic per NON-EMPTY interval (2056 addrs total, <=G hits each)
    for (int t = tid; t < NI; t += TPB) {
        const unsigned lo = imn[t], hi = imx[t];
        if (lo != 0xFFFFFFFFu) atomicMin(&gmin[b * NI + t], lo);
        if (hi != 0u)          atomicMax(&gmax[b * NI + t], hi);
    }

    // deterministic block reduce of dir-1 sum + valid count
    for (int off = 32; off; off >>= 1) {
        sum += __shfl_down(sum, off);
        cnt += __shfl_down(cnt, off);
    }
    __shared__ float r4[4]; __shared__ int i4[4];
    if ((tid & 63) == 0) { r4[tid >> 6] = sum; i4[tid >> 6] = cnt; }
    __syncthreads();
    if (tid == 0) {
        sumA_part[blockIdx.x] = r4[0] + r4[1] + r4[2] + r4[3];
        cnt_part [blockIdx.x] = i4[0] + i4[1] + i4[2] + i4[3];
    }
}

// ---- kernel 3: tiny finalize (1 block): partial sums + scans + mean ----
__global__ __launch_bounds__(TPB) void k_final(
    const float* __restrict__ sbins,
    const float* __restrict__ sumA_part, const int* __restrict__ cnt_part,
    const unsigned* __restrict__ gmin, const unsigned* __restrict__ gmax,
    int B, float* __restrict__ out)
{
    const int tid = threadIdx.x;
    __shared__ float pm[NB], sm[NB];
    __shared__ float r4[4]; __shared__ int i4[4]; __shared__ float q4[4];
    __shared__ float ssa[8]; __shared__ int sn[8];

    // per-batch dir-1 sum + valid count (Lmax needs all batches first)
    for (int bb = 0; bb < B; ++bb) {
        float s = 0.f; int cc = 0;
        for (int k = tid; k < G; k += TPB) {      // G==TPB/2: one coalesced round
            s  += sumA_part[bb * G + k];
            cc += cnt_part [bb * G + k];
        }
        for (int off = 32; off; off >>= 1) { s += __shfl_down(s, off); cc += __shfl_down(cc, off); }
        if ((tid & 63) == 0) { r4[tid >> 6] = s; i4[tid >> 6] = cc; }
        __syncthreads();
        if (tid == 0) { ssa[bb] = r4[0]+r4[1]+r4[2]+r4[3]; sn[bb] = i4[0]+i4[1]+i4[2]+i4[3]; }
        __syncthreads();
    }
    int Lmax = 0;
    for (int bb = 0; bb < B; ++bb) Lmax = max(Lmax, sn[bb]);

    float total = 0.f;
    for (int bb = 0; bb < B; ++bb) {
        // interval max (for pred, entries 0..255) / min (for succ, entries 1..256)
        const unsigned hib = gmax[bb * NI + tid];
        const unsigned lob = gmin[bb * NI + tid + 1];
        pm[tid] = (hib == 0u)          ? -MINF : __uint_as_float(hib);
        sm[tid] = (lob == 0xFFFFFFFFu) ?  MINF : __uint_as_float(lob);
        __syncthreads();
        // fused Hillis-Steele: inclusive prefix-max(pm) + inclusive suffix-min(sm)
        for (int off = 1; off < NB; off <<= 1) {
            const float vp = pm[tid], vs = sm[tid];
            const float op = (tid >= off)     ? pm[tid - off] : -MINF;
            const float os = (tid + off < NB) ? sm[tid + off] :  MINF;
            __syncthreads();
            pm[tid] = fmaxf(vp, op);
            sm[tid] = fminf(vs, os);
            __syncthreads();
        }
        // bin tid: pred = max point < c, succ = min point >= c
        const float cj = sbins[bb * NB + tid];
        const float c2 = cj * cj;
        const float d  = fminf(fminf(cj - pm[tid], sm[tid] - cj), CAPD);
        float bm = d * d;                       // == 1e30 (BIG) if no valid points
        const int npad = Lmax - sn[bb];
        if (npad > 0) bm = fminf(bm, c2);       // pad points sit at 0 -> dist c^2
        float s = bm, mc = c2;
        for (int off = 32; off; off >>= 1) {
            s  += __shfl_down(s, off);
            mc  = fminf(mc, __shfl_down(mc, off));
        }
        if ((tid & 63) == 0) { r4[tid >> 6] = s; q4[tid >> 6] = mc; }
        __syncthreads();
        if (tid == 0)
            total += ssa[bb]
                   + (float)npad * fminf(fminf(q4[0], q4[1]), fminf(q4[2], q4[3]))
                   + (r4[0] + r4[1] + r4[2] + r4[3]);
        __syncthreads();
    }
    if (tid == 0) out[0] = total / (float)B;    // batch_reduction = mean
}

extern "C" void kernel_launch(void* const* d_in, const int* in_sizes, int n_in,
                              void* d_out, int out_size, void* d_ws, size_t ws_size,
                              hipStream_t stream) {
    const float* bc = (const float*)d_in[0];    // [B, 256, 1]
    const float* gt = (const float*)d_in[1];    // [B, 1, H, W]
    const int B  = in_sizes[0] / NB;            // 4
    const int V  = in_sizes[1] / B;             // 157696
    const int CH = (V + G - 1) / G;             // 1232

    float*    sbins     = (float*)d_ws;                         // [B, NB]
    float*    sumA_part = sbins + (size_t)B * NB;               // [B*G]
    int*      cnt_part  = (int*)(sumA_part + (size_t)B * G);    // [B*G]
    unsigned* gmin      = (unsigned*)(cnt_part + (size_t)B * G);// [B, NI]
    unsigned* gmax      = gmin + (size_t)B * NI;                // [B, NI]

    k_sort <<<B, NB, 0, stream>>>(bc, sbins, gmin, gmax);
    k_main <<<B * G, TPB, 0, stream>>>(sbins, gt, V, CH,
                                       sumA_part, cnt_part, gmin, gmax);
    k_final<<<1, TPB, 0, stream>>>(sbins, sumA_part, cnt_part,
                                   gmin, gmax, B, (float*)d_out);
}